// Round 5
// baseline (355.660 us; speedup 1.0000x reference)
//
#include <hip/hip_runtime.h>

#define H 16
#define DH 64
#define S 2048
#define E 1024
#define NB 4

typedef short short8_t __attribute__((ext_vector_type(8)));
typedef float float4_t __attribute__((ext_vector_type(4)));
typedef float float16_t __attribute__((ext_vector_type(16)));

__device__ inline unsigned short f2bf(float f) {
    union { float f; unsigned u; } v; v.f = f;
    unsigned r = v.u + 0x7fffu + ((v.u >> 16) & 1u);
    return (unsigned short)(r >> 16);
}

// rne-pack two fp32 -> one dword of 2 bf16 (lo = a, hi = b)
__device__ __forceinline__ unsigned pk_bf16(float a, float b) {
    union { float f; unsigned u; } ua, ub;
    ua.f = a; ub.f = b;
    unsigned ra = ua.u + 0x7fffu + ((ua.u >> 16) & 1u);
    unsigned rb = ub.u + 0x7fffu + ((ub.u >> 16) & 1u);
    return __builtin_amdgcn_perm(rb, ra, 0x07060302u);
}

// single-instruction rne pack (lo = a, hi = b)
__device__ __forceinline__ unsigned cvt_pk_bf16(float a, float b) {
    unsigned r;
    asm("v_cvt_pk_bf16_f32 %0, %1, %2" : "=v"(r) : "v"(a), "v"(b));
    return r;
}

__device__ __forceinline__ float16_t mfma32(short8_t a, short8_t b, float16_t c) {
    return __builtin_amdgcn_mfma_f32_32x32x16_bf16(a, b, c, 0, 0, 0);
}

// async global->LDS, 16B per lane; lds base must be wave-uniform (HW writes
// base + lane*16). Caller arranges swizzle on the GLOBAL side.
__device__ __forceinline__ void async_copy16(const unsigned short* g, unsigned short* l) {
    __builtin_amdgcn_global_load_lds(
        (const __attribute__((address_space(1))) unsigned int*)g,
        (__attribute__((address_space(3))) unsigned int*)l, 16, 0, 0);
}

// ---------------------------------------------------------------------------
// x fp32 -> bf16 convert (values/keys/query), 8 elems/thread
// ---------------------------------------------------------------------------
__global__ __launch_bounds__(256) void xcvt_kernel(
    const float* __restrict__ v, const float* __restrict__ k,
    const float* __restrict__ q, unsigned short* __restrict__ xv,
    unsigned short* __restrict__ xk, unsigned short* __restrict__ xq)
{
    const int z = blockIdx.y;
    const float* src = (z == 0) ? v : (z == 1) ? k : q;
    unsigned short* dst = (z == 0) ? xv : (z == 1) ? xk : xq;
    size_t i0 = ((size_t)blockIdx.x * 256 + threadIdx.x) * 8;
    float4 f0 = *reinterpret_cast<const float4*>(src + i0);
    float4 f1 = *reinterpret_cast<const float4*>(src + i0 + 4);
    uint4 o;
    o.x = pk_bf16(f0.x, f0.y); o.y = pk_bf16(f0.z, f0.w);
    o.z = pk_bf16(f1.x, f1.y); o.w = pk_bf16(f1.z, f1.w);
    *reinterpret_cast<uint4*>(dst + i0) = o;
}

// ---------------------------------------------------------------------------
// Weight transpose + fp32->bf16 convert: W[K][N] -> Wt[N][K] (bf16), 4 weights
// ---------------------------------------------------------------------------
__global__ __launch_bounds__(256) void wcvt_kernel(
    const float* __restrict__ Wv, const float* __restrict__ Wk,
    const float* __restrict__ Wq, const float* __restrict__ Wo,
    unsigned short* __restrict__ Wt)
{
    __shared__ float tile[64][65];
    const float* W = (blockIdx.z == 0) ? Wv : (blockIdx.z == 1) ? Wk
                   : (blockIdx.z == 2) ? Wq : Wo;
    unsigned short* out = Wt + (size_t)blockIdx.z * (E * E);
    const int k0 = blockIdx.x * 64, n0 = blockIdx.y * 64;
    const int tid = threadIdx.x;
#pragma unroll
    for (int i = 0; i < 4; ++i) {
        int c = i * 256 + tid;
        int kl = c >> 4, nl4 = (c & 15) * 4;
        float4 v = *reinterpret_cast<const float4*>(W + (size_t)(k0 + kl) * E + n0 + nl4);
        tile[kl][nl4 + 0] = v.x; tile[kl][nl4 + 1] = v.y;
        tile[kl][nl4 + 2] = v.z; tile[kl][nl4 + 3] = v.w;
    }
    __syncthreads();
#pragma unroll
    for (int i = 0; i < 4; ++i) {
        int c = i * 256 + tid;
        int nl = c >> 4, kl4 = (c & 15) * 4;
        ushort4 o;
        o.x = f2bf(tile[kl4 + 0][nl]); o.y = f2bf(tile[kl4 + 1][nl]);
        o.z = f2bf(tile[kl4 + 2][nl]); o.w = f2bf(tile[kl4 + 3][nl]);
        *reinterpret_cast<ushort4*>(out + (size_t)(n0 + nl) * E + k0 + kl4) = o;
    }
}

// ---------------------------------------------------------------------------
// Projection GEMM, 512 THREADS (8 waves, wave grid 4x2, 32x64 out each):
// 2 blocks x 8 waves = 16 waves/CU (50% occ) vs the old 256-thread 25%.
// DOUBLE-BUFFERED K-loop, one barrier/iter. C = A(bf16 [8192][1024]) @ W + b.
// WT is W^T bf16 [N][K]. MODE 0: out = v^T [n][h][d][s] with operands SWAPPED
// (D rows = n/d, D cols = m/s; 32B-contiguous stores) AND s-bits 2<->3 swapped
// so flash's PV V-fragment is one contiguous b128 in LDS slot order.
// MODE 1: [n][h][s][d]. LDS unpadded; chunk c of row r stored at c^(r&7).
// ---------------------------------------------------------------------------
template<int MODE>
__global__ __launch_bounds__(512, 4) void proj_kernel(
    const unsigned short* __restrict__ A, const unsigned short* __restrict__ WT,
    const float* __restrict__ bias, unsigned short* __restrict__ out)
{
    __shared__ __align__(16) unsigned short As[2][128][64];
    __shared__ __align__(16) unsigned short Bs[2][128][64];

    const int tid = threadIdx.x;
    const int m0 = blockIdx.y * 128;
    const int n0 = blockIdx.x * 128;
    const int wave = tid >> 6, lane = tid & 63;
    const int wm = wave >> 1, wn = wave & 1;      // wm 0..3, wn 0..1
    const int quad = lane >> 4, l16 = lane & 15;
    const int r8 = lane >> 3;
    const int c8 = (lane & 7) ^ (r8 & 7);

    constexpr int AX = (MODE == 0) ? 4 : 2;
    constexpr int AY = (MODE == 0) ? 2 : 4;
    float4_t acc[AX][AY];
#pragma unroll
    for (int i = 0; i < AX; ++i)
#pragma unroll
        for (int j = 0; j < AY; ++j) { float4_t z = {0.f,0.f,0.f,0.f}; acc[i][j] = z; }

    // prologue: prefetch K-tile 0 into buf 0 (2 instrs each for A and B)
#pragma unroll
    for (int j = 0; j < 2; ++j) {
        int row = j * 64 + wave * 8 + r8;
        async_copy16(A  + (size_t)(m0 + row) * E + c8 * 8, &As[0][j * 64 + wave * 8][0]);
        async_copy16(WT + (size_t)(n0 + row) * E + c8 * 8, &Bs[0][j * 64 + wave * 8][0]);
    }

    for (int it = 0; it < 16; ++it) {
        const int cur = it & 1, nxt = cur ^ 1;
        __syncthreads();   // tile `it` resident (vmcnt+lgkm drained per wave)

        if (it < 15) {
            const int kn = (it + 1) * 64;
#pragma unroll
            for (int j = 0; j < 2; ++j) {
                int row = j * 64 + wave * 8 + r8;
                async_copy16(A  + (size_t)(m0 + row) * E + kn + c8 * 8, &As[nxt][j * 64 + wave * 8][0]);
                async_copy16(WT + (size_t)(n0 + row) * E + kn + c8 * 8, &Bs[nxt][j * 64 + wave * 8][0]);
            }
        }
#pragma unroll
        for (int kk = 0; kk < 2; ++kk) {
            short8_t a[2], b[4];
#pragma unroll
            for (int mi = 0; mi < 2; ++mi)
                a[mi] = *reinterpret_cast<const short8_t*>(
                    &As[cur][wm * 32 + mi * 16 + l16][((kk * 4 + quad) ^ (l16 & 7)) * 8]);
#pragma unroll
            for (int nj = 0; nj < 4; ++nj)
                b[nj] = *reinterpret_cast<const short8_t*>(
                    &Bs[cur][wn * 64 + nj * 16 + l16][((kk * 4 + quad) ^ (l16 & 7)) * 8]);
#pragma unroll
            for (int x = 0; x < AX; ++x)
#pragma unroll
                for (int y = 0; y < AY; ++y) {
                    if constexpr (MODE == 0)
                        acc[x][y] = __builtin_amdgcn_mfma_f32_16x16x32_bf16(b[x], a[y], acc[x][y], 0, 0, 0);
                    else
                        acc[x][y] = __builtin_amdgcn_mfma_f32_16x16x32_bf16(a[x], b[y], acc[x][y], 0, 0, 0);
                }
        }
    }

    if constexpr (MODE == 0) {
        // D rows (quad*4+r) = n-dim (h,d), D cols (l16) = m-dim (s).
        // Store with s-bits 2<->3 swapped (vt slot order for flash PV b128).
#pragma unroll
        for (int x = 0; x < AX; ++x) {
            float4 bb = *reinterpret_cast<const float4*>(&bias[n0 + wn * 64 + x * 16 + quad * 4]);
#pragma unroll
            for (int y = 0; y < AY; ++y) {
                int m = m0 + wm * 32 + y * 16 + l16;
                int nn = m >> 11, s = m & 2047;
                int sp = (s & ~12) | (((s >> 2) & 1) << 3) | (((s >> 3) & 1) << 2);
#pragma unroll
                for (int r = 0; r < 4; ++r) {
                    int gcol = n0 + wn * 64 + x * 16 + quad * 4 + r;
                    int h = gcol >> 6, d = gcol & 63;
                    float val = acc[x][y][r] + ((const float*)&bb)[r];
                    out[(((size_t)(nn * H + h)) * DH + d) * S + sp] = f2bf(val);
                }
            }
        }
    } else {
#pragma unroll
        for (int x = 0; x < AX; ++x) {
#pragma unroll
            for (int y = 0; y < AY; ++y) {
                int gcol = n0 + wn * 64 + y * 16 + l16;
                float bvv = bias[gcol];
                int h = gcol >> 6, d = gcol & 63;
#pragma unroll
                for (int r = 0; r < 4; ++r) {
                    int gm = m0 + wm * 32 + x * 16 + quad * 4 + r;
                    float val = acc[x][y][r] + bvv;
                    int nn = gm >> 11, s = gm & 2047;
                    out[(((size_t)(nn * H + h)) * S + s) * DH + d] = f2bf(val);
                }
            }
        }
    }
}

// ---------------------------------------------------------------------------
// Flash attention, fixed-max softmax (exact; shift M=16 applied to num+denom).
// 4 waves x 32 q-rows (256 threads), 32x32x16 MFMA for BOTH QK^T and PV.
// PV trick: MFMA contracts slot-k of A vs slot-k of B; the S^T D-fragment's
// native kv<->slot permutation is applied to BOTH P (cvt_pk of D regs) and V.
// vt is stored with kv-bits 2<->3 swapped (by proj<0>), so the V B-fragment
// is ONE contiguous b128 read in LDS slot order -> zero cross-lane exchange,
// zero assembly movs. K/V double-buffered via global_load_lds + XOR swizzle;
// ONE barrier/tile; XCD-swizzled block ids (8 heads/XCD, K/V L2-resident).
// ---------------------------------------------------------------------------
__global__ __launch_bounds__(256, 4) void flash_kernel(
    const unsigned short* __restrict__ Qb, const unsigned short* __restrict__ Kb,
    const unsigned short* __restrict__ VTb, const int* __restrict__ mask,
    unsigned short* __restrict__ AO)
{
    __shared__ __align__(16) unsigned short Ks[2][64][64];
    __shared__ __align__(16) unsigned short Vs[2][64][64];
    __shared__ __align__(16) float am[2][64];
    __shared__ __align__(16) float lbuf[4][32];

    const int tid = threadIdx.x;
    const int wave = tid >> 6, lane = tid & 63;
    const int l32 = lane & 31, hf = lane >> 5;
    const int r8 = lane >> 3;
    const int c8 = (lane & 7) ^ (r8 & 7);

    // bijective XCD swizzle: 1024 blocks, 8 XCDs -> XCD k gets heads [k*8,(k+1)*8)
    const int wlin = blockIdx.y * 16 + blockIdx.x;
    const int wid = (wlin & 7) * 128 + (wlin >> 3);
    const int qt = wid & 15;
    const int nh = wid >> 4;
    const int n = nh >> 4, h = nh & 15;
    const size_t hb = (size_t)nh * S * DH;
    const unsigned short* Qh = Qb + hb;
    const unsigned short* Kh = Kb + hb;
    const unsigned short* Vh = VTb + hb;
    const int* mp = mask + n * S;

    const float c1 = 0.03125f * 1.4426950408889634f;   // (1/sqrt(E)) * log2e
    const float C2_UNMASK = -23.083120654223414f;      // -16*log2e
    const float C2_MASK   = -1.44e20f;

    // Q fragments (B operand of S^T = K·Q^T): lane holds q = base+l32,
    // dh = ks*16 + hf*8 + {0..7}
    short8_t qa[4];
#pragma unroll
    for (int ks = 0; ks < 4; ++ks) {
        int row = qt * 128 + wave * 32 + l32;
        qa[ks] = *reinterpret_cast<const short8_t*>(Qh + (size_t)row * DH + ks * 16 + hf * 8);
    }

    float16_t o[2];
#pragma unroll
    for (int nb = 0; nb < 2; ++nb)
#pragma unroll
        for (int i = 0; i < 16; ++i) o[nb][i] = 0.f;
    float lsum = 0.f;

    // prologue: prefetch tile 0 into buf 0
#pragma unroll
    for (int j = 0; j < 2; ++j) {
        int row = wave * 16 + j * 8 + r8;
        async_copy16(Kh + (size_t)row * DH + c8 * 8, &Ks[0][wave * 16 + j * 8][0]);
        async_copy16(Vh + (size_t)row * S + c8 * 8,  &Vs[0][wave * 16 + j * 8][0]);
    }
    if (tid < 64) am[0][tid] = (mp[tid] == 0) ? C2_MASK : C2_UNMASK;

    for (int it = 0; it < 32; ++it) {
        const int cur = it & 1, nxt = cur ^ 1;
        __syncthreads();   // tile `it` resident (drains vmcnt+lgkm)

        // prefetch next tile (wraps harmlessly on last iter)
        const int kn = (it < 31) ? (it + 1) * 64 : 0;
#pragma unroll
        for (int j = 0; j < 2; ++j) {
            int row = wave * 16 + j * 8 + r8;
            async_copy16(Kh + (size_t)(kn + row) * DH + c8 * 8, &Ks[nxt][wave * 16 + j * 8][0]);
            async_copy16(Vh + (size_t)row * S + kn + c8 * 8,    &Vs[nxt][wave * 16 + j * 8][0]);
        }
        if (tid < 64) am[nxt][tid] = (mp[kn + tid] == 0) ? C2_MASK : C2_UNMASK;

        // per kv-halftile (32 kv rows): S^T via 32x32x16, then softmax to w[]
        // w[kvb][g][0..1]: cvt_pk'd P for D regs 4g..4g+3 (kv = 32kvb+8g+4hf+{0..3})
        unsigned w[2][4][2];
#pragma unroll
        for (int kvb = 0; kvb < 2; ++kvb) {
            float16_t st;
#pragma unroll
            for (int i = 0; i < 16; ++i) st[i] = 0.f;
            __builtin_amdgcn_s_setprio(1);
#pragma unroll
            for (int ks = 0; ks < 4; ++ks) {
                // A-frag: row kv = kvb*32 + l32, dh chunk = (ks*2+hf) ^ (row&7)
                short8_t ak = *reinterpret_cast<const short8_t*>(
                    &Ks[cur][kvb * 32 + l32][((ks * 2 + hf) ^ (l32 & 7)) * 8]);
                st = mfma32(ak, qa[ks], st);
            }
            __builtin_amdgcn_s_setprio(0);
#pragma unroll
            for (int g = 0; g < 4; ++g) {
                float4 c2v = *reinterpret_cast<const float4*>(&am[cur][kvb * 32 + g * 8 + hf * 4]);
                float p0 = __builtin_amdgcn_exp2f(st[g * 4 + 0] * c1 + c2v.x);
                float p1 = __builtin_amdgcn_exp2f(st[g * 4 + 1] * c1 + c2v.y);
                float p2 = __builtin_amdgcn_exp2f(st[g * 4 + 2] * c1 + c2v.z);
                float p3 = __builtin_amdgcn_exp2f(st[g * 4 + 3] * c1 + c2v.w);
                lsum += (p0 + p1) + (p2 + p3);
                w[kvb][g][0] = cvt_pk_bf16(p0, p1);
                w[kvb][g][1] = cvt_pk_bf16(p2, p3);
            }
        }

        // O += P·V via 32x32x16. vt's kv-bit-2<->3 swap means LDS holds slot
        // order [4hf+0..3, 8+4hf+0..3] contiguously per (t,hf): ONE b128 read.
        __builtin_amdgcn_s_setprio(1);
#pragma unroll
        for (int ks2 = 0; ks2 < 4; ++ks2) {
            const int kvb = ks2 >> 1, t = ks2 & 1;
            union { unsigned u[4]; short8_t s; } pu;
            pu.u[0] = w[kvb][t * 2][0];     pu.u[1] = w[kvb][t * 2][1];
            pu.u[2] = w[kvb][t * 2 + 1][0]; pu.u[3] = w[kvb][t * 2 + 1][1];
#pragma unroll
            for (int nb = 0; nb < 2; ++nb) {
                const int d = nb * 32 + l32;
                short8_t vb = *reinterpret_cast<const short8_t*>(
                    &Vs[cur][d][((kvb * 4 + t * 2 + hf) ^ (d & 7)) * 8]);
                o[nb] = mfma32(pu.s, vb, o[nb]);
            }
        }
        __builtin_amdgcn_s_setprio(0);
    }

    // denom: lane holds sum for q-col l32 over its kv rows; fold halves
    lsum += __shfl_xor(lsum, 32);
    if (lane < 32) lbuf[wave][lane] = lsum;

#pragma unroll
    for (int g = 0; g < 4; ++g) {
        float4 dn = *reinterpret_cast<const float4*>(&lbuf[wave][g * 8 + hf * 4]);
#pragma unroll
        for (int r = 0; r < 4; ++r) {
            float invl = __builtin_amdgcn_rcpf(((const float*)&dn)[r]);
            int row = g * 8 + hf * 4 + r;                 // D row = (reg&3)+8*(reg>>2)+4*hf
            int qrow = qt * 128 + wave * 32 + row;
            size_t gm = (size_t)n * S + qrow;
#pragma unroll
            for (int nb = 0; nb < 2; ++nb) {
                int col = h * DH + nb * 32 + l32;
                AO[gm * E + col] = f2bf(o[nb][g * 4 + r] * invl);
            }
        }
    }
}

// ---------------------------------------------------------------------------
// Output GEMM, 512 THREADS (8 waves, 4x2 wave grid), DOUBLE-BUFFERED:
// out(fp32) = AO(bf16) @ Wo + bo.
// ---------------------------------------------------------------------------
__global__ __launch_bounds__(512, 4) void ogemm_kernel(
    const unsigned short* __restrict__ A, const unsigned short* __restrict__ WT,
    const float* __restrict__ bias, float* __restrict__ out)
{
    __shared__ __align__(16) unsigned short As[2][128][64];
    __shared__ __align__(16) unsigned short Bs[2][128][64];

    const int tid = threadIdx.x;
    const int m0 = blockIdx.y * 128;
    const int n0 = blockIdx.x * 128;
    const int wave = tid >> 6, lane = tid & 63;
    const int wm = wave >> 1, wn = wave & 1;      // wm 0..3, wn 0..1
    const int quad = lane >> 4, l16 = lane & 15;
    const int r8 = lane >> 3;
    const int c8 = (lane & 7) ^ (r8 & 7);

    float4_t acc[2][4];
#pragma unroll
    for (int i = 0; i < 2; ++i)
#pragma unroll
        for (int j = 0; j < 4; ++j) { float4_t z = {0.f,0.f,0.f,0.f}; acc[i][j] = z; }

#pragma unroll
    for (int j = 0; j < 2; ++j) {
        int row = j * 64 + wave * 8 + r8;
        async_copy16(A  + (size_t)(m0 + row) * E + c8 * 8, &As[0][j * 64 + wave * 8][0]);
        async_copy16(WT + (size_t)(n0 + row) * E + c8 * 8, &Bs[0][j * 64 + wave * 8][0]);
    }

    for (int it = 0; it < 16; ++it) {
        const int cur = it & 1, nxt = cur ^ 1;
        __syncthreads();

        if (it < 15) {
            const int kn = (it + 1) * 64;
#pragma unroll
            for (int j = 0; j < 2; ++j) {
                int row = j * 64 + wave * 8 + r8;
                async_copy16(A  + (size_t)(m0 + row) * E + kn + c8 * 8, &As[nxt][j * 64 + wave * 8][0]);
                async_copy16(WT + (size_t)(n0 + row) * E + kn + c8 * 8, &Bs[nxt][j * 64 + wave * 8][0]);
            }
        }
#pragma unroll
        for (int kk = 0; kk < 2; ++kk) {
            short8_t a[2], b[4];
#pragma unroll
            for (int mi = 0; mi < 2; ++mi)
                a[mi] = *reinterpret_cast<const short8_t*>(
                    &As[cur][wm * 32 + mi * 16 + l16][((kk * 4 + quad) ^ (l16 & 7)) * 8]);
#pragma unroll
            for (int nj = 0; nj < 4; ++nj)
                b[nj] = *reinterpret_cast<const short8_t*>(
                    &Bs[cur][wn * 64 + nj * 16 + l16][((kk * 4 + quad) ^ (l16 & 7)) * 8]);
#pragma unroll
            for (int mi = 0; mi < 2; ++mi)
#pragma unroll
                for (int nj = 0; nj < 4; ++nj)
                    acc[mi][nj] = __builtin_amdgcn_mfma_f32_16x16x32_bf16(a[mi], b[nj], acc[mi][nj], 0, 0, 0);
        }
    }
#pragma unroll
    for (int mi = 0; mi < 2; ++mi)
#pragma unroll
        for (int nj = 0; nj < 4; ++nj) {
            int gcol = n0 + wn * 64 + nj * 16 + l16;
            float bvv = bias[gcol];
#pragma unroll
            for (int r = 0; r < 4; ++r) {
                int gm = m0 + wm * 32 + mi * 16 + quad * 4 + r;
                out[(size_t)gm * E + gcol] = acc[mi][nj][r] + bvv;
            }
        }
}

extern "C" void kernel_launch(void* const* d_in, const int* in_sizes, int n_in,
                              void* d_out, int out_size, void* d_ws, size_t ws_size,
                              hipStream_t stream) {
    const float* values = (const float*)d_in[0];
    const float* keys   = (const float*)d_in[1];
    const float* query  = (const float*)d_in[2];
    const int*   mask   = (const int*)d_in[3];
    const float* Wv = (const float*)d_in[4];  const float* bv = (const float*)d_in[5];
    const float* Wk = (const float*)d_in[6];  const float* bk = (const float*)d_in[7];
    const float* Wq = (const float*)d_in[8];  const float* bq = (const float*)d_in[9];
    const float* Wo = (const float*)d_in[10]; const float* bo = (const float*)d_in[11];
    float* out = (float*)d_out;

    // ws layout (72 MB; aliasing relies on sequential launch order on stream):
    //  [0,8)    Wt (4 weights, bf16, transposed)
    //  [8,24)   xv  -> later reused as kb
    //  [24,40)  xk  -> later reused as qb
    //  [40,56)  xq  -> later reused as ao
    //  [56,72)  vt
    char* ws = (char*)d_ws;
    unsigned short* Wt = (unsigned short*)ws;
    unsigned short* xv = (unsigned short*)(ws + 8388608);
    unsigned short* xk = (unsigned short*)(ws + 25165824);
    unsigned short* xq = (unsigned short*)(ws + 41943040);
    unsigned short* vt = (unsigned short*)(ws + 58720256);
    unsigned short* kb = xv;   // proj-k writes after proj-v consumed xv
    unsigned short* qb = xk;   // proj-q writes after proj-k consumed xk
    unsigned short* ao = xq;   // flash writes after proj-q consumed xq

    xcvt_kernel<<<dim3(4096, 3), 256, 0, stream>>>(values, keys, query, xv, xk, xq);
    wcvt_kernel<<<dim3(16, 16, 4), 256, 0, stream>>>(Wv, Wk, Wq, Wo, Wt);
    proj_kernel<0><<<dim3(8, 64), 512, 0, stream>>>(xv, Wt,           bv, vt);
    proj_kernel<1><<<dim3(8, 64), 512, 0, stream>>>(xk, Wt + 1048576, bk, kb);
    proj_kernel<1><<<dim3(8, 64), 512, 0, stream>>>(xq, Wt + 2097152, bq, qb);
    flash_kernel<<<dim3(16, 64), 256, 0, stream>>>(qb, kb, vt, mask, ao);
    ogemm_kernel<<<dim3(8, 64), 512, 0, stream>>>(ao, Wt + 3145728, bo, out);
}

// Round 6
// 352.012 us; speedup vs baseline: 1.0104x; 1.0104x over previous
//
#include <hip/hip_runtime.h>

#define H 16
#define DH 64
#define S 2048
#define E 1024
#define NB 4

typedef short short8_t __attribute__((ext_vector_type(8)));
typedef float float4_t __attribute__((ext_vector_type(4)));
typedef float float16_t __attribute__((ext_vector_type(16)));

__device__ inline unsigned short f2bf(float f) {
    union { float f; unsigned u; } v; v.f = f;
    unsigned r = v.u + 0x7fffu + ((v.u >> 16) & 1u);
    return (unsigned short)(r >> 16);
}

// rne-pack two fp32 -> one dword of 2 bf16 (lo = a, hi = b)
__device__ __forceinline__ unsigned pk_bf16(float a, float b) {
    union { float f; unsigned u; } ua, ub;
    ua.f = a; ub.f = b;
    unsigned ra = ua.u + 0x7fffu + ((ua.u >> 16) & 1u);
    unsigned rb = ub.u + 0x7fffu + ((ub.u >> 16) & 1u);
    return __builtin_amdgcn_perm(rb, ra, 0x07060302u);
}

// single-instruction rne pack (lo = a, hi = b)
__device__ __forceinline__ unsigned cvt_pk_bf16(float a, float b) {
    unsigned r;
    asm("v_cvt_pk_bf16_f32 %0, %1, %2" : "=v"(r) : "v"(a), "v"(b));
    return r;
}

__device__ __forceinline__ float16_t mfma32(short8_t a, short8_t b, float16_t c) {
    return __builtin_amdgcn_mfma_f32_32x32x16_bf16(a, b, c, 0, 0, 0);
}

// async global->LDS, 16B per lane; lds base must be wave-uniform (HW writes
// base + lane*16). Caller arranges swizzle on the GLOBAL side.
__device__ __forceinline__ void async_copy16(const unsigned short* g, unsigned short* l) {
    __builtin_amdgcn_global_load_lds(
        (const __attribute__((address_space(1))) unsigned int*)g,
        (__attribute__((address_space(3))) unsigned int*)l, 16, 0, 0);
}

// ---------------------------------------------------------------------------
// x fp32 -> bf16 convert (values/keys/query), 8 elems/thread
// ---------------------------------------------------------------------------
__global__ __launch_bounds__(256) void xcvt_kernel(
    const float* __restrict__ v, const float* __restrict__ k,
    const float* __restrict__ q, unsigned short* __restrict__ xv,
    unsigned short* __restrict__ xk, unsigned short* __restrict__ xq)
{
    const int z = blockIdx.y;
    const float* src = (z == 0) ? v : (z == 1) ? k : q;
    unsigned short* dst = (z == 0) ? xv : (z == 1) ? xk : xq;
    size_t i0 = ((size_t)blockIdx.x * 256 + threadIdx.x) * 8;
    float4 f0 = *reinterpret_cast<const float4*>(src + i0);
    float4 f1 = *reinterpret_cast<const float4*>(src + i0 + 4);
    uint4 o;
    o.x = pk_bf16(f0.x, f0.y); o.y = pk_bf16(f0.z, f0.w);
    o.z = pk_bf16(f1.x, f1.y); o.w = pk_bf16(f1.z, f1.w);
    *reinterpret_cast<uint4*>(dst + i0) = o;
}

// ---------------------------------------------------------------------------
// Weight transpose + fp32->bf16 convert: W[K][N] -> Wt[N][K] (bf16), 4 weights
// ---------------------------------------------------------------------------
__global__ __launch_bounds__(256) void wcvt_kernel(
    const float* __restrict__ Wv, const float* __restrict__ Wk,
    const float* __restrict__ Wq, const float* __restrict__ Wo,
    unsigned short* __restrict__ Wt)
{
    __shared__ float tile[64][65];
    const float* W = (blockIdx.z == 0) ? Wv : (blockIdx.z == 1) ? Wk
                   : (blockIdx.z == 2) ? Wq : Wo;
    unsigned short* out = Wt + (size_t)blockIdx.z * (E * E);
    const int k0 = blockIdx.x * 64, n0 = blockIdx.y * 64;
    const int tid = threadIdx.x;
#pragma unroll
    for (int i = 0; i < 4; ++i) {
        int c = i * 256 + tid;
        int kl = c >> 4, nl4 = (c & 15) * 4;
        float4 v = *reinterpret_cast<const float4*>(W + (size_t)(k0 + kl) * E + n0 + nl4);
        tile[kl][nl4 + 0] = v.x; tile[kl][nl4 + 1] = v.y;
        tile[kl][nl4 + 2] = v.z; tile[kl][nl4 + 3] = v.w;
    }
    __syncthreads();
#pragma unroll
    for (int i = 0; i < 4; ++i) {
        int c = i * 256 + tid;
        int nl = c >> 4, kl4 = (c & 15) * 4;
        ushort4 o;
        o.x = f2bf(tile[kl4 + 0][nl]); o.y = f2bf(tile[kl4 + 1][nl]);
        o.z = f2bf(tile[kl4 + 2][nl]); o.w = f2bf(tile[kl4 + 3][nl]);
        *reinterpret_cast<ushort4*>(out + (size_t)(n0 + nl) * E + k0 + kl4) = o;
    }
}

// ---------------------------------------------------------------------------
// Projection GEMM, 256 threads, SINGLE-BUFFERED (m97 structure: stage ->
// barrier -> compute -> barrier). 32 KB LDS -> 4 blocks/CU = 16 waves/CU,
// cross-block overlap hides the staging drain (vs 2 blocks/CU with dbuf).
// C = A(bf16 [8192][1024]) @ W + b. WT is W^T bf16 [N][K].
// MODE 0: out = v^T [n][h][d][s], operands SWAPPED (D rows = n/d, D cols =
// m/s; 32B-contiguous stores) AND s-bits 2<->3 swapped so flash's PV
// V-fragment is one contiguous b128 in LDS slot order. MODE 1: [n][h][s][d].
// LDS unpadded (row = 128 B); chunk c of row r stored at c^(r&7).
// ---------------------------------------------------------------------------
template<int MODE>
__global__ __launch_bounds__(256, 3) void proj_kernel(
    const unsigned short* __restrict__ A, const unsigned short* __restrict__ WT,
    const float* __restrict__ bias, unsigned short* __restrict__ out)
{
    __shared__ __align__(16) unsigned short As[128][64];
    __shared__ __align__(16) unsigned short Bs[128][64];

    const int tid = threadIdx.x;
    const int m0 = blockIdx.y * 128;
    const int n0 = blockIdx.x * 128;
    const int wave = tid >> 6, lane = tid & 63;
    const int wm = wave >> 1, wn = wave & 1;
    const int quad = lane >> 4, l16 = lane & 15;
    const int r8 = lane >> 3;
    const int c8 = (lane & 7) ^ (r8 & 7);

    float4_t acc[4][4];
#pragma unroll
    for (int i = 0; i < 4; ++i)
#pragma unroll
        for (int j = 0; j < 4; ++j) { float4_t z = {0.f,0.f,0.f,0.f}; acc[i][j] = z; }

    for (int it = 0; it < 16; ++it) {
        const int kn = it * 64;
        // stage tile `it` (async copies; vmcnt drained at the barrier)
#pragma unroll
        for (int j = 0; j < 4; ++j) {
            int row = wave * 32 + j * 8 + r8;
            async_copy16(A  + (size_t)(m0 + row) * E + kn + c8 * 8, &As[wave * 32 + j * 8][0]);
            async_copy16(WT + (size_t)(n0 + row) * E + kn + c8 * 8, &Bs[wave * 32 + j * 8][0]);
        }
        __syncthreads();   // all waves' copies drained -> LDS tile valid
#pragma unroll
        for (int kk = 0; kk < 2; ++kk) {
            short8_t a[4], b[4];
#pragma unroll
            for (int mi = 0; mi < 4; ++mi)
                a[mi] = *reinterpret_cast<const short8_t*>(
                    &As[wm * 64 + mi * 16 + l16][((kk * 4 + quad) ^ (l16 & 7)) * 8]);
#pragma unroll
            for (int nj = 0; nj < 4; ++nj)
                b[nj] = *reinterpret_cast<const short8_t*>(
                    &Bs[wn * 64 + nj * 16 + l16][((kk * 4 + quad) ^ (l16 & 7)) * 8]);
#pragma unroll
            for (int x = 0; x < 4; ++x)
#pragma unroll
                for (int y = 0; y < 4; ++y) {
                    if constexpr (MODE == 0)
                        acc[x][y] = __builtin_amdgcn_mfma_f32_16x16x32_bf16(b[x], a[y], acc[x][y], 0, 0, 0);
                    else
                        acc[x][y] = __builtin_amdgcn_mfma_f32_16x16x32_bf16(a[x], b[y], acc[x][y], 0, 0, 0);
                }
        }
        __syncthreads();   // all reads done before next stage overwrites
    }

    if constexpr (MODE == 0) {
        // D rows (quad*4+r) = n-dim (h,d), D cols (l16) = m-dim (s).
        // Store with s-bits 2<->3 swapped (vt slot order for flash PV b128).
#pragma unroll
        for (int x = 0; x < 4; ++x) {
            float4 bb = *reinterpret_cast<const float4*>(&bias[n0 + wn * 64 + x * 16 + quad * 4]);
#pragma unroll
            for (int y = 0; y < 4; ++y) {
                int m = m0 + wm * 64 + y * 16 + l16;
                int nn = m >> 11, s = m & 2047;
                int sp = (s & ~12) | (((s >> 2) & 1) << 3) | (((s >> 3) & 1) << 2);
#pragma unroll
                for (int r = 0; r < 4; ++r) {
                    int gcol = n0 + wn * 64 + x * 16 + quad * 4 + r;
                    int h = gcol >> 6, d = gcol & 63;
                    float val = acc[x][y][r] + ((const float*)&bb)[r];
                    out[(((size_t)(nn * H + h)) * DH + d) * S + sp] = f2bf(val);
                }
            }
        }
    } else {
#pragma unroll
        for (int x = 0; x < 4; ++x) {
#pragma unroll
            for (int y = 0; y < 4; ++y) {
                int gcol = n0 + wn * 64 + y * 16 + l16;
                float bvv = bias[gcol];
                int h = gcol >> 6, d = gcol & 63;
#pragma unroll
                for (int r = 0; r < 4; ++r) {
                    int gm = m0 + wm * 64 + x * 16 + quad * 4 + r;
                    float val = acc[x][y][r] + bvv;
                    int nn = gm >> 11, s = gm & 2047;
                    out[(((size_t)(nn * H + h)) * S + s) * DH + d] = f2bf(val);
                }
            }
        }
    }
}

// ---------------------------------------------------------------------------
// Flash attention, fixed-max softmax (exact; shift M=16 applied to num+denom).
// 4 waves x 32 q-rows (256 threads), 32x32x16 MFMA for BOTH QK^T and PV.
// PV trick: MFMA contracts slot-k of A vs slot-k of B; the S^T D-fragment's
// native kv<->slot permutation is applied to BOTH P (cvt_pk of D regs) and V.
// vt is stored with kv-bits 2<->3 swapped (by proj<0>), so the V B-fragment
// is ONE contiguous b128 read in LDS slot order -> zero cross-lane exchange.
// K/V double-buffered via global_load_lds + XOR swizzle; ONE barrier/tile;
// XCD-swizzled block ids (8 heads/XCD, K/V L2-resident).
// ---------------------------------------------------------------------------
__global__ __launch_bounds__(256, 4) void flash_kernel(
    const unsigned short* __restrict__ Qb, const unsigned short* __restrict__ Kb,
    const unsigned short* __restrict__ VTb, const int* __restrict__ mask,
    unsigned short* __restrict__ AO)
{
    __shared__ __align__(16) unsigned short Ks[2][64][64];
    __shared__ __align__(16) unsigned short Vs[2][64][64];
    __shared__ __align__(16) float am[2][64];
    __shared__ __align__(16) float lbuf[4][32];

    const int tid = threadIdx.x;
    const int wave = tid >> 6, lane = tid & 63;
    const int l32 = lane & 31, hf = lane >> 5;
    const int r8 = lane >> 3;
    const int c8 = (lane & 7) ^ (r8 & 7);

    // bijective XCD swizzle: 1024 blocks, 8 XCDs -> XCD k gets heads [k*8,(k+1)*8)
    const int wlin = blockIdx.y * 16 + blockIdx.x;
    const int wid = (wlin & 7) * 128 + (wlin >> 3);
    const int qt = wid & 15;
    const int nh = wid >> 4;
    const int n = nh >> 4, h = nh & 15;
    const size_t hb = (size_t)nh * S * DH;
    const unsigned short* Qh = Qb + hb;
    const unsigned short* Kh = Kb + hb;
    const unsigned short* Vh = VTb + hb;
    const int* mp = mask + n * S;

    const float c1 = 0.03125f * 1.4426950408889634f;   // (1/sqrt(E)) * log2e
    const float C2_UNMASK = -23.083120654223414f;      // -16*log2e
    const float C2_MASK   = -1.44e20f;

    // Q fragments (B operand of S^T = K·Q^T): lane holds q = base+l32,
    // dh = ks*16 + hf*8 + {0..7}
    short8_t qa[4];
#pragma unroll
    for (int ks = 0; ks < 4; ++ks) {
        int row = qt * 128 + wave * 32 + l32;
        qa[ks] = *reinterpret_cast<const short8_t*>(Qh + (size_t)row * DH + ks * 16 + hf * 8);
    }

    float16_t o[2];
#pragma unroll
    for (int nb = 0; nb < 2; ++nb)
#pragma unroll
        for (int i = 0; i < 16; ++i) o[nb][i] = 0.f;
    float lsum = 0.f;

    // prologue: prefetch tile 0 into buf 0
#pragma unroll
    for (int j = 0; j < 2; ++j) {
        int row = wave * 16 + j * 8 + r8;
        async_copy16(Kh + (size_t)row * DH + c8 * 8, &Ks[0][wave * 16 + j * 8][0]);
        async_copy16(Vh + (size_t)row * S + c8 * 8,  &Vs[0][wave * 16 + j * 8][0]);
    }
    if (tid < 64) am[0][tid] = (mp[tid] == 0) ? C2_MASK : C2_UNMASK;

    for (int it = 0; it < 32; ++it) {
        const int cur = it & 1, nxt = cur ^ 1;
        __syncthreads();   // tile `it` resident (drains vmcnt+lgkm)

        // prefetch next tile (wraps harmlessly on last iter)
        const int kn = (it < 31) ? (it + 1) * 64 : 0;
#pragma unroll
        for (int j = 0; j < 2; ++j) {
            int row = wave * 16 + j * 8 + r8;
            async_copy16(Kh + (size_t)(kn + row) * DH + c8 * 8, &Ks[nxt][wave * 16 + j * 8][0]);
            async_copy16(Vh + (size_t)row * S + kn + c8 * 8,    &Vs[nxt][wave * 16 + j * 8][0]);
        }
        if (tid < 64) am[nxt][tid] = (mp[kn + tid] == 0) ? C2_MASK : C2_UNMASK;

        // per kv-halftile (32 kv rows): S^T via 32x32x16, then softmax to w[]
        // w[kvb][g][0..1]: cvt_pk'd P for D regs 4g..4g+3 (kv = 32kvb+8g+4hf+{0..3})
        unsigned w[2][4][2];
#pragma unroll
        for (int kvb = 0; kvb < 2; ++kvb) {
            float16_t st;
#pragma unroll
            for (int i = 0; i < 16; ++i) st[i] = 0.f;
            __builtin_amdgcn_s_setprio(1);
#pragma unroll
            for (int ks = 0; ks < 4; ++ks) {
                // A-frag: row kv = kvb*32 + l32, dh chunk = (ks*2+hf) ^ (row&7)
                short8_t ak = *reinterpret_cast<const short8_t*>(
                    &Ks[cur][kvb * 32 + l32][((ks * 2 + hf) ^ (l32 & 7)) * 8]);
                st = mfma32(ak, qa[ks], st);
            }
            __builtin_amdgcn_s_setprio(0);
#pragma unroll
            for (int g = 0; g < 4; ++g) {
                float4 c2v = *reinterpret_cast<const float4*>(&am[cur][kvb * 32 + g * 8 + hf * 4]);
                float p0 = __builtin_amdgcn_exp2f(st[g * 4 + 0] * c1 + c2v.x);
                float p1 = __builtin_amdgcn_exp2f(st[g * 4 + 1] * c1 + c2v.y);
                float p2 = __builtin_amdgcn_exp2f(st[g * 4 + 2] * c1 + c2v.z);
                float p3 = __builtin_amdgcn_exp2f(st[g * 4 + 3] * c1 + c2v.w);
                lsum += (p0 + p1) + (p2 + p3);
                w[kvb][g][0] = cvt_pk_bf16(p0, p1);
                w[kvb][g][1] = cvt_pk_bf16(p2, p3);
            }
        }

        // O += P·V via 32x32x16. vt's kv-bit-2<->3 swap means LDS holds slot
        // order [4hf+0..3, 8+4hf+0..3] contiguously per (t,hf): ONE b128 read.
        __builtin_amdgcn_s_setprio(1);
#pragma unroll
        for (int ks2 = 0; ks2 < 4; ++ks2) {
            const int kvb = ks2 >> 1, t = ks2 & 1;
            union { unsigned u[4]; short8_t s; } pu;
            pu.u[0] = w[kvb][t * 2][0];     pu.u[1] = w[kvb][t * 2][1];
            pu.u[2] = w[kvb][t * 2 + 1][0]; pu.u[3] = w[kvb][t * 2 + 1][1];
#pragma unroll
            for (int nb = 0; nb < 2; ++nb) {
                const int d = nb * 32 + l32;
                short8_t vb = *reinterpret_cast<const short8_t*>(
                    &Vs[cur][d][((kvb * 4 + t * 2 + hf) ^ (d & 7)) * 8]);
                o[nb] = mfma32(pu.s, vb, o[nb]);
            }
        }
        __builtin_amdgcn_s_setprio(0);
    }

    // denom: lane holds sum for q-col l32 over its kv rows; fold halves
    lsum += __shfl_xor(lsum, 32);
    if (lane < 32) lbuf[wave][lane] = lsum;

#pragma unroll
    for (int g = 0; g < 4; ++g) {
        float4 dn = *reinterpret_cast<const float4*>(&lbuf[wave][g * 8 + hf * 4]);
#pragma unroll
        for (int r = 0; r < 4; ++r) {
            float invl = __builtin_amdgcn_rcpf(((const float*)&dn)[r]);
            int row = g * 8 + hf * 4 + r;                 // D row = (reg&3)+8*(reg>>2)+4*hf
            int qrow = qt * 128 + wave * 32 + row;
            size_t gm = (size_t)n * S + qrow;
#pragma unroll
            for (int nb = 0; nb < 2; ++nb) {
                int col = h * DH + nb * 32 + l32;
                AO[gm * E + col] = f2bf(o[nb][g * 4 + r] * invl);
            }
        }
    }
}

// ---------------------------------------------------------------------------
// Output GEMM, 256 threads, SINGLE-BUFFERED (m97 structure), 32 KB LDS ->
// 4 blocks/CU: out(fp32) = AO(bf16) @ Wo + bo.
// ---------------------------------------------------------------------------
__global__ __launch_bounds__(256, 3) void ogemm_kernel(
    const unsigned short* __restrict__ A, const unsigned short* __restrict__ WT,
    const float* __restrict__ bias, float* __restrict__ out)
{
    __shared__ __align__(16) unsigned short As[128][64];
    __shared__ __align__(16) unsigned short Bs[128][64];

    const int tid = threadIdx.x;
    const int m0 = blockIdx.y * 128;
    const int n0 = blockIdx.x * 128;
    const int wave = tid >> 6, lane = tid & 63;
    const int wm = wave >> 1, wn = wave & 1;
    const int quad = lane >> 4, l16 = lane & 15;
    const int r8 = lane >> 3;
    const int c8 = (lane & 7) ^ (r8 & 7);

    float4_t acc[4][4];
#pragma unroll
    for (int i = 0; i < 4; ++i)
#pragma unroll
        for (int j = 0; j < 4; ++j) { float4_t z = {0.f,0.f,0.f,0.f}; acc[i][j] = z; }

    for (int it = 0; it < 16; ++it) {
        const int kn = it * 64;
#pragma unroll
        for (int j = 0; j < 4; ++j) {
            int row = wave * 32 + j * 8 + r8;
            async_copy16(A  + (size_t)(m0 + row) * E + kn + c8 * 8, &As[wave * 32 + j * 8][0]);
            async_copy16(WT + (size_t)(n0 + row) * E + kn + c8 * 8, &Bs[wave * 32 + j * 8][0]);
        }
        __syncthreads();
#pragma unroll
        for (int kk = 0; kk < 2; ++kk) {
            short8_t a[4], b[4];
#pragma unroll
            for (int mi = 0; mi < 4; ++mi)
                a[mi] = *reinterpret_cast<const short8_t*>(
                    &As[wm * 64 + mi * 16 + l16][((kk * 4 + quad) ^ (l16 & 7)) * 8]);
#pragma unroll
            for (int nj = 0; nj < 4; ++nj)
                b[nj] = *reinterpret_cast<const short8_t*>(
                    &Bs[wn * 64 + nj * 16 + l16][((kk * 4 + quad) ^ (l16 & 7)) * 8]);
#pragma unroll
            for (int mi = 0; mi < 4; ++mi)
#pragma unroll
                for (int nj = 0; nj < 4; ++nj)
                    acc[mi][nj] = __builtin_amdgcn_mfma_f32_16x16x32_bf16(a[mi], b[nj], acc[mi][nj], 0, 0, 0);
        }
        __syncthreads();
    }
#pragma unroll
    for (int mi = 0; mi < 4; ++mi)
#pragma unroll
        for (int nj = 0; nj < 4; ++nj) {
            int gcol = n0 + wn * 64 + nj * 16 + l16;
            float bvv = bias[gcol];
#pragma unroll
            for (int r = 0; r < 4; ++r) {
                int gm = m0 + wm * 64 + mi * 16 + quad * 4 + r;
                out[(size_t)gm * E + gcol] = acc[mi][nj][r] + bvv;
            }
        }
}

extern "C" void kernel_launch(void* const* d_in, const int* in_sizes, int n_in,
                              void* d_out, int out_size, void* d_ws, size_t ws_size,
                              hipStream_t stream) {
    const float* values = (const float*)d_in[0];
    const float* keys   = (const float*)d_in[1];
    const float* query  = (const float*)d_in[2];
    const int*   mask   = (const int*)d_in[3];
    const float* Wv = (const float*)d_in[4];  const float* bv = (const float*)d_in[5];
    const float* Wk = (const float*)d_in[6];  const float* bk = (const float*)d_in[7];
    const float* Wq = (const float*)d_in[8];  const float* bq = (const float*)d_in[9];
    const float* Wo = (const float*)d_in[10]; const float* bo = (const float*)d_in[11];
    float* out = (float*)d_out;

    // ws layout (72 MB; aliasing relies on sequential launch order on stream):
    //  [0,8)    Wt (4 weights, bf16, transposed)
    //  [8,24)   xv  -> later reused as kb
    //  [24,40)  xk  -> later reused as qb
    //  [40,56)  xq  -> later reused as ao
    //  [56,72)  vt
    char* ws = (char*)d_ws;
    unsigned short* Wt = (unsigned short*)ws;
    unsigned short* xv = (unsigned short*)(ws + 8388608);
    unsigned short* xk = (unsigned short*)(ws + 25165824);
    unsigned short* xq = (unsigned short*)(ws + 41943040);
    unsigned short* vt = (unsigned short*)(ws + 58720256);
    unsigned short* kb = xv;   // proj-k writes after proj-v consumed xv
    unsigned short* qb = xk;   // proj-q writes after proj-k consumed xk
    unsigned short* ao = xq;   // flash writes after proj-q consumed xq

    xcvt_kernel<<<dim3(4096, 3), 256, 0, stream>>>(values, keys, query, xv, xk, xq);
    wcvt_kernel<<<dim3(16, 16, 4), 256, 0, stream>>>(Wv, Wk, Wq, Wo, Wt);
    proj_kernel<0><<<dim3(8, 64), 256, 0, stream>>>(xv, Wt,           bv, vt);
    proj_kernel<1><<<dim3(8, 64), 256, 0, stream>>>(xk, Wt + 1048576, bk, kb);
    proj_kernel<1><<<dim3(8, 64), 256, 0, stream>>>(xq, Wt + 2097152, bq, qb);
    flash_kernel<<<dim3(16, 64), 256, 0, stream>>>(qb, kb, vt, mask, ao);
    ogemm_kernel<<<dim3(8, 64), 256, 0, stream>>>(ao, Wt + 3145728, bo, out);
}

// Round 7
// 343.459 us; speedup vs baseline: 1.0355x; 1.0249x over previous
//
#include <hip/hip_runtime.h>

#define H 16
#define DH 64
#define S 2048
#define E 1024
#define NB 4

typedef short short8_t __attribute__((ext_vector_type(8)));
typedef float float4_t __attribute__((ext_vector_type(4)));
typedef float float16_t __attribute__((ext_vector_type(16)));

__device__ inline unsigned short f2bf(float f) {
    union { float f; unsigned u; } v; v.f = f;
    unsigned r = v.u + 0x7fffu + ((v.u >> 16) & 1u);
    return (unsigned short)(r >> 16);
}

// rne-pack two fp32 -> one dword of 2 bf16 (lo = a, hi = b)
__device__ __forceinline__ unsigned pk_bf16(float a, float b) {
    union { float f; unsigned u; } ua, ub;
    ua.f = a; ub.f = b;
    unsigned ra = ua.u + 0x7fffu + ((ua.u >> 16) & 1u);
    unsigned rb = ub.u + 0x7fffu + ((ub.u >> 16) & 1u);
    return __builtin_amdgcn_perm(rb, ra, 0x07060302u);
}

// single-instruction rne pack (lo = a, hi = b)
__device__ __forceinline__ unsigned cvt_pk_bf16(float a, float b) {
    unsigned r;
    asm("v_cvt_pk_bf16_f32 %0, %1, %2" : "=v"(r) : "v"(a), "v"(b));
    return r;
}

__device__ __forceinline__ float16_t mfma32(short8_t a, short8_t b, float16_t c) {
    return __builtin_amdgcn_mfma_f32_32x32x16_bf16(a, b, c, 0, 0, 0);
}

// async global->LDS, 16B per lane; lds base must be wave-uniform (HW writes
// base + lane*16). Caller arranges swizzle on the GLOBAL side.
__device__ __forceinline__ void async_copy16(const unsigned short* g, unsigned short* l) {
    __builtin_amdgcn_global_load_lds(
        (const __attribute__((address_space(1))) unsigned int*)g,
        (__attribute__((address_space(3))) unsigned int*)l, 16, 0, 0);
}

// ---------------------------------------------------------------------------
// x fp32 -> bf16 convert (values/keys/query), 8 elems/thread
// ---------------------------------------------------------------------------
__global__ __launch_bounds__(256) void xcvt_kernel(
    const float* __restrict__ v, const float* __restrict__ k,
    const float* __restrict__ q, unsigned short* __restrict__ xv,
    unsigned short* __restrict__ xk, unsigned short* __restrict__ xq)
{
    const int z = blockIdx.y;
    const float* src = (z == 0) ? v : (z == 1) ? k : q;
    unsigned short* dst = (z == 0) ? xv : (z == 1) ? xk : xq;
    size_t i0 = ((size_t)blockIdx.x * 256 + threadIdx.x) * 8;
    float4 f0 = *reinterpret_cast<const float4*>(src + i0);
    float4 f1 = *reinterpret_cast<const float4*>(src + i0 + 4);
    uint4 o;
    o.x = pk_bf16(f0.x, f0.y); o.y = pk_bf16(f0.z, f0.w);
    o.z = pk_bf16(f1.x, f1.y); o.w = pk_bf16(f1.z, f1.w);
    *reinterpret_cast<uint4*>(dst + i0) = o;
}

// ---------------------------------------------------------------------------
// Weight transpose + fp32->bf16 convert: W[K][N] -> Wt[N][K] (bf16), 4 weights
// ---------------------------------------------------------------------------
__global__ __launch_bounds__(256) void wcvt_kernel(
    const float* __restrict__ Wv, const float* __restrict__ Wk,
    const float* __restrict__ Wq, const float* __restrict__ Wo,
    unsigned short* __restrict__ Wt)
{
    __shared__ float tile[64][65];
    const float* W = (blockIdx.z == 0) ? Wv : (blockIdx.z == 1) ? Wk
                   : (blockIdx.z == 2) ? Wq : Wo;
    unsigned short* out = Wt + (size_t)blockIdx.z * (E * E);
    const int k0 = blockIdx.x * 64, n0 = blockIdx.y * 64;
    const int tid = threadIdx.x;
#pragma unroll
    for (int i = 0; i < 4; ++i) {
        int c = i * 256 + tid;
        int kl = c >> 4, nl4 = (c & 15) * 4;
        float4 v = *reinterpret_cast<const float4*>(W + (size_t)(k0 + kl) * E + n0 + nl4);
        tile[kl][nl4 + 0] = v.x; tile[kl][nl4 + 1] = v.y;
        tile[kl][nl4 + 2] = v.z; tile[kl][nl4 + 3] = v.w;
    }
    __syncthreads();
#pragma unroll
    for (int i = 0; i < 4; ++i) {
        int c = i * 256 + tid;
        int nl = c >> 4, kl4 = (c & 15) * 4;
        ushort4 o;
        o.x = f2bf(tile[kl4 + 0][nl]); o.y = f2bf(tile[kl4 + 1][nl]);
        o.z = f2bf(tile[kl4 + 2][nl]); o.w = f2bf(tile[kl4 + 3][nl]);
        *reinterpret_cast<ushort4*>(out + (size_t)(n0 + nl) * E + k0 + kl4) = o;
    }
}

// ---------------------------------------------------------------------------
// Projection GEMM, 256 threads, DOUBLE-BUFFERED K-loop (best measured config:
// one barrier/iter, prefetch next tile before computing current).
// XCD-SWIZZLED block ids: XCD k owns m-tiles [8k,8k+8) x all 8 n-tiles ->
// per-XCD working set = 2MB A-panel + 2MB WT = 4MB, L2-resident staging.
// C = A(bf16 [8192][1024]) @ W + b. WT is W^T bf16 [N][K].
// MODE 0: out = v^T [n][h][d][s], operands SWAPPED (D rows = n/d, D cols =
// m/s; 32B-contiguous stores) AND s-bits 2<->3 swapped so flash's PV
// V-fragment is one contiguous b128 in LDS slot order. MODE 1: [n][h][s][d].
// LDS unpadded (row = 128 B); chunk c of row r stored at c^(r&7).
// ---------------------------------------------------------------------------
template<int MODE>
__global__ __launch_bounds__(256) void proj_kernel(
    const unsigned short* __restrict__ A, const unsigned short* __restrict__ WT,
    const float* __restrict__ bias, unsigned short* __restrict__ out)
{
    __shared__ __align__(16) unsigned short As[2][128][64];
    __shared__ __align__(16) unsigned short Bs[2][128][64];

    const int tid = threadIdx.x;
    // bijective XCD swizzle over 512 blocks: wid = (wlin&7)*64 + wlin/8
    const int wlin = blockIdx.y * 8 + blockIdx.x;
    const int wid = (wlin & 7) * 64 + (wlin >> 3);
    const int n0 = (wid & 7) * 128;
    const int m0 = (wid >> 3) * 128;
    const int wave = tid >> 6, lane = tid & 63;
    const int wm = wave >> 1, wn = wave & 1;
    const int quad = lane >> 4, l16 = lane & 15;
    const int r8 = lane >> 3;
    const int c8 = (lane & 7) ^ (r8 & 7);

    float4_t acc[4][4];
#pragma unroll
    for (int i = 0; i < 4; ++i)
#pragma unroll
        for (int j = 0; j < 4; ++j) { float4_t z = {0.f,0.f,0.f,0.f}; acc[i][j] = z; }

    // prologue: prefetch K-tile 0 into buf 0
#pragma unroll
    for (int j = 0; j < 4; ++j) {
        int row = wave * 32 + j * 8 + r8;
        async_copy16(A  + (size_t)(m0 + row) * E + c8 * 8, &As[0][wave * 32 + j * 8][0]);
        async_copy16(WT + (size_t)(n0 + row) * E + c8 * 8, &Bs[0][wave * 32 + j * 8][0]);
    }

    for (int it = 0; it < 16; ++it) {
        const int cur = it & 1, nxt = cur ^ 1;
        __syncthreads();   // tile `it` resident (vmcnt+lgkm drained per wave)

        if (it < 15) {
            const int kn = (it + 1) * 64;
#pragma unroll
            for (int j = 0; j < 4; ++j) {
                int row = wave * 32 + j * 8 + r8;
                async_copy16(A  + (size_t)(m0 + row) * E + kn + c8 * 8, &As[nxt][wave * 32 + j * 8][0]);
                async_copy16(WT + (size_t)(n0 + row) * E + kn + c8 * 8, &Bs[nxt][wave * 32 + j * 8][0]);
            }
        }
#pragma unroll
        for (int kk = 0; kk < 2; ++kk) {
            short8_t a[4], b[4];
#pragma unroll
            for (int mi = 0; mi < 4; ++mi)
                a[mi] = *reinterpret_cast<const short8_t*>(
                    &As[cur][wm * 64 + mi * 16 + l16][((kk * 4 + quad) ^ (l16 & 7)) * 8]);
#pragma unroll
            for (int nj = 0; nj < 4; ++nj)
                b[nj] = *reinterpret_cast<const short8_t*>(
                    &Bs[cur][wn * 64 + nj * 16 + l16][((kk * 4 + quad) ^ (l16 & 7)) * 8]);
#pragma unroll
            for (int x = 0; x < 4; ++x)
#pragma unroll
                for (int y = 0; y < 4; ++y) {
                    if constexpr (MODE == 0)
                        acc[x][y] = __builtin_amdgcn_mfma_f32_16x16x32_bf16(b[x], a[y], acc[x][y], 0, 0, 0);
                    else
                        acc[x][y] = __builtin_amdgcn_mfma_f32_16x16x32_bf16(a[x], b[y], acc[x][y], 0, 0, 0);
                }
        }
    }

    if constexpr (MODE == 0) {
        // D rows (quad*4+r) = n-dim (h,d), D cols (l16) = m-dim (s).
        // Store with s-bits 2<->3 swapped (vt slot order for flash PV b128).
#pragma unroll
        for (int x = 0; x < 4; ++x) {
            float4 bb = *reinterpret_cast<const float4*>(&bias[n0 + wn * 64 + x * 16 + quad * 4]);
#pragma unroll
            for (int y = 0; y < 4; ++y) {
                int m = m0 + wm * 64 + y * 16 + l16;
                int nn = m >> 11, s = m & 2047;
                int sp = (s & ~12) | (((s >> 2) & 1) << 3) | (((s >> 3) & 1) << 2);
#pragma unroll
                for (int r = 0; r < 4; ++r) {
                    int gcol = n0 + wn * 64 + x * 16 + quad * 4 + r;
                    int h = gcol >> 6, d = gcol & 63;
                    float val = acc[x][y][r] + ((const float*)&bb)[r];
                    out[(((size_t)(nn * H + h)) * DH + d) * S + sp] = f2bf(val);
                }
            }
        }
    } else {
#pragma unroll
        for (int x = 0; x < 4; ++x) {
#pragma unroll
            for (int y = 0; y < 4; ++y) {
                int gcol = n0 + wn * 64 + y * 16 + l16;
                float bvv = bias[gcol];
                int h = gcol >> 6, d = gcol & 63;
#pragma unroll
                for (int r = 0; r < 4; ++r) {
                    int gm = m0 + wm * 64 + x * 16 + quad * 4 + r;
                    float val = acc[x][y][r] + bvv;
                    int nn = gm >> 11, s = gm & 2047;
                    out[(((size_t)(nn * H + h)) * S + s) * DH + d] = f2bf(val);
                }
            }
        }
    }
}

// ---------------------------------------------------------------------------
// Flash attention, fixed-max softmax (exact; shift M=16 applied to num+denom).
// 4 waves x 32 q-rows (256 threads), 32x32x16 MFMA for BOTH QK^T and PV.
// PV trick: MFMA contracts slot-k of A vs slot-k of B; the S^T D-fragment's
// native kv<->slot permutation is applied to BOTH P (cvt_pk of D regs) and V.
// vt is stored with kv-bits 2<->3 swapped (by proj<0>), so the V B-fragment
// is ONE contiguous b128 read in LDS slot order -> zero cross-lane exchange.
// K/V double-buffered via global_load_lds + XOR swizzle; ONE barrier/tile;
// XCD-swizzled block ids (8 heads/XCD, K/V L2-resident).
// ---------------------------------------------------------------------------
__global__ __launch_bounds__(256, 4) void flash_kernel(
    const unsigned short* __restrict__ Qb, const unsigned short* __restrict__ Kb,
    const unsigned short* __restrict__ VTb, const int* __restrict__ mask,
    unsigned short* __restrict__ AO)
{
    __shared__ __align__(16) unsigned short Ks[2][64][64];
    __shared__ __align__(16) unsigned short Vs[2][64][64];
    __shared__ __align__(16) float am[2][64];
    __shared__ __align__(16) float lbuf[4][32];

    const int tid = threadIdx.x;
    const int wave = tid >> 6, lane = tid & 63;
    const int l32 = lane & 31, hf = lane >> 5;
    const int r8 = lane >> 3;
    const int c8 = (lane & 7) ^ (r8 & 7);

    // bijective XCD swizzle: 1024 blocks, 8 XCDs -> XCD k gets heads [k*8,(k+1)*8)
    const int wlin = blockIdx.y * 16 + blockIdx.x;
    const int wid = (wlin & 7) * 128 + (wlin >> 3);
    const int qt = wid & 15;
    const int nh = wid >> 4;
    const int n = nh >> 4, h = nh & 15;
    const size_t hb = (size_t)nh * S * DH;
    const unsigned short* Qh = Qb + hb;
    const unsigned short* Kh = Kb + hb;
    const unsigned short* Vh = VTb + hb;
    const int* mp = mask + n * S;

    const float c1 = 0.03125f * 1.4426950408889634f;   // (1/sqrt(E)) * log2e
    const float C2_UNMASK = -23.083120654223414f;      // -16*log2e
    const float C2_MASK   = -1.44e20f;

    // Q fragments (B operand of S^T = K·Q^T): lane holds q = base+l32,
    // dh = ks*16 + hf*8 + {0..7}
    short8_t qa[4];
#pragma unroll
    for (int ks = 0; ks < 4; ++ks) {
        int row = qt * 128 + wave * 32 + l32;
        qa[ks] = *reinterpret_cast<const short8_t*>(Qh + (size_t)row * DH + ks * 16 + hf * 8);
    }

    float16_t o[2];
#pragma unroll
    for (int nb = 0; nb < 2; ++nb)
#pragma unroll
        for (int i = 0; i < 16; ++i) o[nb][i] = 0.f;
    float lsum = 0.f;

    // prologue: prefetch tile 0 into buf 0
#pragma unroll
    for (int j = 0; j < 2; ++j) {
        int row = wave * 16 + j * 8 + r8;
        async_copy16(Kh + (size_t)row * DH + c8 * 8, &Ks[0][wave * 16 + j * 8][0]);
        async_copy16(Vh + (size_t)row * S + c8 * 8,  &Vs[0][wave * 16 + j * 8][0]);
    }
    if (tid < 64) am[0][tid] = (mp[tid] == 0) ? C2_MASK : C2_UNMASK;

    for (int it = 0; it < 32; ++it) {
        const int cur = it & 1, nxt = cur ^ 1;
        __syncthreads();   // tile `it` resident (drains vmcnt+lgkm)

        // prefetch next tile (wraps harmlessly on last iter)
        const int kn = (it < 31) ? (it + 1) * 64 : 0;
#pragma unroll
        for (int j = 0; j < 2; ++j) {
            int row = wave * 16 + j * 8 + r8;
            async_copy16(Kh + (size_t)(kn + row) * DH + c8 * 8, &Ks[nxt][wave * 16 + j * 8][0]);
            async_copy16(Vh + (size_t)row * S + kn + c8 * 8,    &Vs[nxt][wave * 16 + j * 8][0]);
        }
        if (tid < 64) am[nxt][tid] = (mp[kn + tid] == 0) ? C2_MASK : C2_UNMASK;

        // per kv-halftile (32 kv rows): S^T via 32x32x16, then softmax to w[]
        // w[kvb][g][0..1]: cvt_pk'd P for D regs 4g..4g+3 (kv = 32kvb+8g+4hf+{0..3})
        unsigned w[2][4][2];
#pragma unroll
        for (int kvb = 0; kvb < 2; ++kvb) {
            float16_t st;
#pragma unroll
            for (int i = 0; i < 16; ++i) st[i] = 0.f;
            __builtin_amdgcn_s_setprio(1);
#pragma unroll
            for (int ks = 0; ks < 4; ++ks) {
                // A-frag: row kv = kvb*32 + l32, dh chunk = (ks*2+hf) ^ (row&7)
                short8_t ak = *reinterpret_cast<const short8_t*>(
                    &Ks[cur][kvb * 32 + l32][((ks * 2 + hf) ^ (l32 & 7)) * 8]);
                st = mfma32(ak, qa[ks], st);
            }
            __builtin_amdgcn_s_setprio(0);
#pragma unroll
            for (int g = 0; g < 4; ++g) {
                float4 c2v = *reinterpret_cast<const float4*>(&am[cur][kvb * 32 + g * 8 + hf * 4]);
                float p0 = __builtin_amdgcn_exp2f(st[g * 4 + 0] * c1 + c2v.x);
                float p1 = __builtin_amdgcn_exp2f(st[g * 4 + 1] * c1 + c2v.y);
                float p2 = __builtin_amdgcn_exp2f(st[g * 4 + 2] * c1 + c2v.z);
                float p3 = __builtin_amdgcn_exp2f(st[g * 4 + 3] * c1 + c2v.w);
                lsum += (p0 + p1) + (p2 + p3);
                w[kvb][g][0] = cvt_pk_bf16(p0, p1);
                w[kvb][g][1] = cvt_pk_bf16(p2, p3);
            }
        }

        // O += P·V via 32x32x16. vt's kv-bit-2<->3 swap means LDS holds slot
        // order [4hf+0..3, 8+4hf+0..3] contiguously per (t,hf): ONE b128 read.
        __builtin_amdgcn_s_setprio(1);
#pragma unroll
        for (int ks2 = 0; ks2 < 4; ++ks2) {
            const int kvb = ks2 >> 1, t = ks2 & 1;
            union { unsigned u[4]; short8_t s; } pu;
            pu.u[0] = w[kvb][t * 2][0];     pu.u[1] = w[kvb][t * 2][1];
            pu.u[2] = w[kvb][t * 2 + 1][0]; pu.u[3] = w[kvb][t * 2 + 1][1];
#pragma unroll
            for (int nb = 0; nb < 2; ++nb) {
                const int d = nb * 32 + l32;
                short8_t vb = *reinterpret_cast<const short8_t*>(
                    &Vs[cur][d][((kvb * 4 + t * 2 + hf) ^ (d & 7)) * 8]);
                o[nb] = mfma32(pu.s, vb, o[nb]);
            }
        }
        __builtin_amdgcn_s_setprio(0);
    }

    // denom: lane holds sum for q-col l32 over its kv rows; fold halves
    lsum += __shfl_xor(lsum, 32);
    if (lane < 32) lbuf[wave][lane] = lsum;

#pragma unroll
    for (int g = 0; g < 4; ++g) {
        float4 dn = *reinterpret_cast<const float4*>(&lbuf[wave][g * 8 + hf * 4]);
#pragma unroll
        for (int r = 0; r < 4; ++r) {
            float invl = __builtin_amdgcn_rcpf(((const float*)&dn)[r]);
            int row = g * 8 + hf * 4 + r;                 // D row = (reg&3)+8*(reg>>2)+4*hf
            int qrow = qt * 128 + wave * 32 + row;
            size_t gm = (size_t)n * S + qrow;
#pragma unroll
            for (int nb = 0; nb < 2; ++nb) {
                int col = h * DH + nb * 32 + l32;
                AO[gm * E + col] = f2bf(o[nb][g * 4 + r] * invl);
            }
        }
    }
}

// ---------------------------------------------------------------------------
// Output GEMM, 256 threads, DOUBLE-BUFFERED, XCD-swizzled block ids:
// out(fp32) = AO(bf16) @ Wo + bo.
// ---------------------------------------------------------------------------
__global__ __launch_bounds__(256) void ogemm_kernel(
    const unsigned short* __restrict__ A, const unsigned short* __restrict__ WT,
    const float* __restrict__ bias, float* __restrict__ out)
{
    __shared__ __align__(16) unsigned short As[2][128][64];
    __shared__ __align__(16) unsigned short Bs[2][128][64];

    const int tid = threadIdx.x;
    const int wlin = blockIdx.y * 8 + blockIdx.x;
    const int wid = (wlin & 7) * 64 + (wlin >> 3);
    const int n0 = (wid & 7) * 128;
    const int m0 = (wid >> 3) * 128;
    const int wave = tid >> 6, lane = tid & 63;
    const int wm = wave >> 1, wn = wave & 1;
    const int quad = lane >> 4, l16 = lane & 15;
    const int r8 = lane >> 3;
    const int c8 = (lane & 7) ^ (r8 & 7);

    float4_t acc[4][4];
#pragma unroll
    for (int i = 0; i < 4; ++i)
#pragma unroll
        for (int j = 0; j < 4; ++j) { float4_t z = {0.f,0.f,0.f,0.f}; acc[i][j] = z; }

#pragma unroll
    for (int j = 0; j < 4; ++j) {
        int row = wave * 32 + j * 8 + r8;
        async_copy16(A  + (size_t)(m0 + row) * E + c8 * 8, &As[0][wave * 32 + j * 8][0]);
        async_copy16(WT + (size_t)(n0 + row) * E + c8 * 8, &Bs[0][wave * 32 + j * 8][0]);
    }

    for (int it = 0; it < 16; ++it) {
        const int cur = it & 1, nxt = cur ^ 1;
        __syncthreads();

        if (it < 15) {
            const int kn = (it + 1) * 64;
#pragma unroll
            for (int j = 0; j < 4; ++j) {
                int row = wave * 32 + j * 8 + r8;
                async_copy16(A  + (size_t)(m0 + row) * E + kn + c8 * 8, &As[nxt][wave * 32 + j * 8][0]);
                async_copy16(WT + (size_t)(n0 + row) * E + kn + c8 * 8, &Bs[nxt][wave * 32 + j * 8][0]);
            }
        }
#pragma unroll
        for (int kk = 0; kk < 2; ++kk) {
            short8_t a[4], b[4];
#pragma unroll
            for (int mi = 0; mi < 4; ++mi)
                a[mi] = *reinterpret_cast<const short8_t*>(
                    &As[cur][wm * 64 + mi * 16 + l16][((kk * 4 + quad) ^ (l16 & 7)) * 8]);
#pragma unroll
            for (int nj = 0; nj < 4; ++nj)
                b[nj] = *reinterpret_cast<const short8_t*>(
                    &Bs[cur][wn * 64 + nj * 16 + l16][((kk * 4 + quad) ^ (l16 & 7)) * 8]);
#pragma unroll
            for (int mi = 0; mi < 4; ++mi)
#pragma unroll
                for (int nj = 0; nj < 4; ++nj)
                    acc[mi][nj] = __builtin_amdgcn_mfma_f32_16x16x32_bf16(a[mi], b[nj], acc[mi][nj], 0, 0, 0);
        }
    }
#pragma unroll
    for (int mi = 0; mi < 4; ++mi)
#pragma unroll
        for (int nj = 0; nj < 4; ++nj) {
            int gcol = n0 + wn * 64 + nj * 16 + l16;
            float bvv = bias[gcol];
#pragma unroll
            for (int r = 0; r < 4; ++r) {
                int gm = m0 + wm * 64 + mi * 16 + quad * 4 + r;
                out[(size_t)gm * E + gcol] = acc[mi][nj][r] + bvv;
            }
        }
}

extern "C" void kernel_launch(void* const* d_in, const int* in_sizes, int n_in,
                              void* d_out, int out_size, void* d_ws, size_t ws_size,
                              hipStream_t stream) {
    const float* values = (const float*)d_in[0];
    const float* keys   = (const float*)d_in[1];
    const float* query  = (const float*)d_in[2];
    const int*   mask   = (const int*)d_in[3];
    const float* Wv = (const float*)d_in[4];  const float* bv = (const float*)d_in[5];
    const float* Wk = (const float*)d_in[6];  const float* bk = (const float*)d_in[7];
    const float* Wq = (const float*)d_in[8];  const float* bq = (const float*)d_in[9];
    const float* Wo = (const float*)d_in[10]; const float* bo = (const float*)d_in[11];
    float* out = (float*)d_out;

    // ws layout (72 MB; aliasing relies on sequential launch order on stream):
    //  [0,8)    Wt (4 weights, bf16, transposed)
    //  [8,24)   xv  -> later reused as kb
    //  [24,40)  xk  -> later reused as qb
    //  [40,56)  xq  -> later reused as ao
    //  [56,72)  vt
    char* ws = (char*)d_ws;
    unsigned short* Wt = (unsigned short*)ws;
    unsigned short* xv = (unsigned short*)(ws + 8388608);
    unsigned short* xk = (unsigned short*)(ws + 25165824);
    unsigned short* xq = (unsigned short*)(ws + 41943040);
    unsigned short* vt = (unsigned short*)(ws + 58720256);
    unsigned short* kb = xv;   // proj-k writes after proj-v consumed xv
    unsigned short* qb = xk;   // proj-q writes after proj-k consumed xk
    unsigned short* ao = xq;   // flash writes after proj-q consumed xq

    xcvt_kernel<<<dim3(4096, 3), 256, 0, stream>>>(values, keys, query, xv, xk, xq);
    wcvt_kernel<<<dim3(16, 16, 4), 256, 0, stream>>>(Wv, Wk, Wq, Wo, Wt);
    proj_kernel<0><<<dim3(8, 64), 256, 0, stream>>>(xv, Wt,           bv, vt);
    proj_kernel<1><<<dim3(8, 64), 256, 0, stream>>>(xk, Wt + 1048576, bk, kb);
    proj_kernel<1><<<dim3(8, 64), 256, 0, stream>>>(xq, Wt + 2097152, bq, qb);
    flash_kernel<<<dim3(16, 64), 256, 0, stream>>>(qb, kb, vt, mask, ao);
    ogemm_kernel<<<dim3(8, 64), 256, 0, stream>>>(ao, Wt + 3145728, bo, out);
}